// Round 1
// baseline (630.052 us; speedup 1.0000x reference)
//
#include <hip/hip_runtime.h>
#include <stdint.h>

// Problem constants
#define Bdim 4
#define Nseq 2048
#define Dmod 1024
#define Hn   16
#define HD   64
#define SCALE 0.03125f   // D^-0.5 = 1/32

typedef __attribute__((ext_vector_type(8))) short short8;
typedef __attribute__((ext_vector_type(8))) unsigned short ushort8;
typedef __attribute__((ext_vector_type(4))) float f32x4;

static __device__ __forceinline__ unsigned short f2bf(float f) {
    union { float f; uint32_t u; } v; v.f = f;
    uint32_t r = (v.u + 0x7FFFu + ((v.u >> 16) & 1u)) >> 16;
    return (unsigned short)r;
}

// ---------------- cast x (fp32 -> bf16), vectorized ----------------
__global__ __launch_bounds__(256) void cast_x_kernel(const float* __restrict__ in,
                                                     unsigned short* __restrict__ out, int n4) {
    int i = blockIdx.x * blockDim.x + threadIdx.x;
    int stride = gridDim.x * blockDim.x;
    for (; i < n4; i += stride) {
        float4 v = reinterpret_cast<const float4*>(in)[i];
        ushort4 o;
        o.x = f2bf(v.x); o.y = f2bf(v.y); o.z = f2bf(v.z); o.w = f2bf(v.w);
        reinterpret_cast<ushort4*>(out)[i] = o;
    }
}

// ---------------- transpose + cast weights: out[c][r] = in[r][c] ----------------
__global__ void transpose_cast_kernel(const float* __restrict__ in,
                                      unsigned short* __restrict__ out, int R, int C) {
    __shared__ unsigned short t[32][33];
    int c0 = blockIdx.x * 32, r0 = blockIdx.y * 32;
    int tx = threadIdx.x, ty = threadIdx.y;
#pragma unroll
    for (int i = 0; i < 4; ++i)
        t[ty + i*8][tx] = f2bf(in[(size_t)(r0 + ty + i*8) * C + c0 + tx]);
    __syncthreads();
#pragma unroll
    for (int i = 0; i < 4; ++i)
        out[(size_t)(c0 + ty + i*8) * R + r0 + tx] = t[tx][ty + i*8];
}

// ---------------- bf16 GEMM: C[M,N] = A[M,K] * Bt[N,K]^T (+bias) ----------------
// 128x128 tile, BK=64, 4 waves (2x2 of 64x64), mfma_f32_16x16x32_bf16
template<bool OUT_BF16, bool BIAS>
__global__ __launch_bounds__(256) void gemm_bt_kernel(const unsigned short* __restrict__ A,
                                                      const unsigned short* __restrict__ Bt,
                                                      void* __restrict__ Cv,
                                                      const float* __restrict__ bias,
                                                      int M, int N, int K) {
    __shared__ unsigned short Al[128][72];
    __shared__ unsigned short Bl[128][72];
    int tid = threadIdx.x;
    int lane = tid & 63, wv = tid >> 6;
    int wr = (wv >> 1) * 64, wc = (wv & 1) * 64;
    int lr = lane & 15, lg = lane >> 4;
    int lk = lg * 8;
    int m0 = blockIdx.y * 128, n0 = blockIdx.x * 128;
    int srow = tid >> 1, scol = (tid & 1) * 32;

    f32x4 acc[4][4];
#pragma unroll
    for (int i = 0; i < 4; ++i)
#pragma unroll
        for (int j = 0; j < 4; ++j) acc[i][j] = (f32x4)0.f;

    for (int k0 = 0; k0 < K; k0 += 64) {
        __syncthreads();
        const ushort8* ag = reinterpret_cast<const ushort8*>(A + (size_t)(m0 + srow) * K + k0 + scol);
        const ushort8* bg = reinterpret_cast<const ushort8*>(Bt + (size_t)(n0 + srow) * K + k0 + scol);
#pragma unroll
        for (int j = 0; j < 4; ++j) {
            *reinterpret_cast<ushort8*>(&Al[srow][scol + j*8]) = ag[j];
            *reinterpret_cast<ushort8*>(&Bl[srow][scol + j*8]) = bg[j];
        }
        __syncthreads();
#pragma unroll
        for (int ks = 0; ks < 2; ++ks) {
            short8 a[4], b[4];
#pragma unroll
            for (int mi = 0; mi < 4; ++mi)
                a[mi] = *reinterpret_cast<const short8*>(&Al[wr + mi*16 + lr][ks*32 + lk]);
#pragma unroll
            for (int nj = 0; nj < 4; ++nj)
                b[nj] = *reinterpret_cast<const short8*>(&Bl[wc + nj*16 + lr][ks*32 + lk]);
#pragma unroll
            for (int mi = 0; mi < 4; ++mi)
#pragma unroll
                for (int nj = 0; nj < 4; ++nj)
                    acc[mi][nj] = __builtin_amdgcn_mfma_f32_16x16x32_bf16(a[mi], b[nj], acc[mi][nj], 0, 0, 0);
        }
    }
#pragma unroll
    for (int mi = 0; mi < 4; ++mi) {
#pragma unroll
        for (int nj = 0; nj < 4; ++nj) {
            int r = m0 + wr + mi*16 + lg*4;
            int c = n0 + wc + nj*16 + lr;
            float bv = BIAS ? bias[c] : 0.f;
#pragma unroll
            for (int i = 0; i < 4; ++i) {
                float v = acc[mi][nj][i] + bv;
                if (OUT_BF16)
                    reinterpret_cast<unsigned short*>(Cv)[(size_t)(r + i) * N + c] = f2bf(v);
                else
                    reinterpret_cast<float*>(Cv)[(size_t)(r + i) * N + c] = v;
            }
        }
    }
}

// ---------------- vT[bh][d][j] = qkv[b*N + j][2048 + h*64 + d] ----------------
__global__ __launch_bounds__(256) void transpose_v_kernel(const unsigned short* __restrict__ qkv,
                                                          unsigned short* __restrict__ vT) {
    __shared__ unsigned short t[64][68];
    int bh = blockIdx.y, b = bh >> 4, h = bh & 15;
    int j0 = blockIdx.x * 64;
    int tid = threadIdx.x;
#pragma unroll
    for (int p = 0; p < 4; ++p) {
        int e = p * 256 + tid;
        int jj = e >> 4;
        int d4 = (e & 15) * 4;
        const unsigned short* src = qkv + (size_t)(b*Nseq + j0 + jj) * 3072 + 2048 + h*64 + d4;
        ushort4 v = *reinterpret_cast<const ushort4*>(src);
        *reinterpret_cast<ushort4*>(&t[jj][d4]) = v;
    }
    __syncthreads();
#pragma unroll
    for (int p = 0; p < 4; ++p) {
        int e = p * 256 + tid;
        int d = e >> 4;
        int j4 = (e & 15) * 4;
        ushort4 v;
        v.x = t[j4 + 0][d]; v.y = t[j4 + 1][d]; v.z = t[j4 + 2][d]; v.w = t[j4 + 3][d];
        *reinterpret_cast<ushort4*>(vT + ((size_t)bh * 64 + d) * Nseq + j0 + j4) = v;
    }
}

// ---------------- flash attention: 4 waves/block, 64 Q rows/wave, KV tile 64 ----------------
__global__ __launch_bounds__(256) void attn_kernel(const unsigned short* __restrict__ qkv,
                                                   const unsigned short* __restrict__ vT,
                                                   unsigned short* __restrict__ attn_o) {
    __shared__ unsigned short Kl[64][72];
    __shared__ unsigned short Vl[64][72];
    __shared__ unsigned short Pl[4][64][72];
    int bh = blockIdx.y, b = bh >> 4, h = bh & 15;
    int tid = threadIdx.x, lane = tid & 63, wv = tid >> 6;
    int lr = lane & 15, lg = lane >> 4, lk = lg * 8;
    int q0 = blockIdx.x * 256 + wv * 64;

    // Q fragments held in registers for the whole kernel
    short8 qf[4][2];
#pragma unroll
    for (int mi = 0; mi < 4; ++mi)
#pragma unroll
        for (int ks = 0; ks < 2; ++ks)
            qf[mi][ks] = *reinterpret_cast<const short8*>(
                qkv + (size_t)(b*Nseq + q0 + mi*16 + lr) * 3072 + h*64 + ks*32 + lk);

    float mrun[16], lrun[16];
    f32x4 oacc[4][4];
#pragma unroll
    for (int i = 0; i < 16; ++i) { mrun[i] = -1e30f; lrun[i] = 0.f; }
#pragma unroll
    for (int i = 0; i < 4; ++i)
#pragma unroll
        for (int j = 0; j < 4; ++j) oacc[i][j] = (f32x4)0.f;

    int srow = tid >> 2, scol = (tid & 3) * 16;
    const unsigned short* vtb = vT + (size_t)bh * 64 * Nseq;

    for (int jt = 0; jt < Nseq; jt += 64) {
        __syncthreads();
        {   // stage K tile [64 kv][64 d] and Vt tile [64 d][64 kv]
            const unsigned short* ksrc = qkv + (size_t)(b*Nseq + jt + srow) * 3072 + 1024 + h*64 + scol;
            *reinterpret_cast<ushort8*>(&Kl[srow][scol])     = *reinterpret_cast<const ushort8*>(ksrc);
            *reinterpret_cast<ushort8*>(&Kl[srow][scol + 8]) = *reinterpret_cast<const ushort8*>(ksrc + 8);
            const unsigned short* vsrc = vtb + (size_t)srow * Nseq + jt + scol;
            *reinterpret_cast<ushort8*>(&Vl[srow][scol])     = *reinterpret_cast<const ushort8*>(vsrc);
            *reinterpret_cast<ushort8*>(&Vl[srow][scol + 8]) = *reinterpret_cast<const ushort8*>(vsrc + 8);
        }
        __syncthreads();

        // S = Q K^T
        f32x4 s[4][4];
#pragma unroll
        for (int i = 0; i < 4; ++i)
#pragma unroll
            for (int j = 0; j < 4; ++j) s[i][j] = (f32x4)0.f;
#pragma unroll
        for (int ks = 0; ks < 2; ++ks) {
            short8 kf[4];
#pragma unroll
            for (int nj = 0; nj < 4; ++nj)
                kf[nj] = *reinterpret_cast<const short8*>(&Kl[nj*16 + lr][ks*32 + lk]);
#pragma unroll
            for (int mi = 0; mi < 4; ++mi)
#pragma unroll
                for (int nj = 0; nj < 4; ++nj)
                    s[mi][nj] = __builtin_amdgcn_mfma_f32_16x16x32_bf16(qf[mi][ks], kf[nj], s[mi][nj], 0, 0, 0);
        }

        // online softmax (rows of this wave; 16-lane groups share a row set)
#pragma unroll
        for (int mi = 0; mi < 4; ++mi) {
#pragma unroll
            for (int i = 0; i < 4; ++i) {
                const int idx = mi*4 + i;
                float t0 = fmaxf(fmaxf(s[mi][0][i], s[mi][1][i]),
                                 fmaxf(s[mi][2][i], s[mi][3][i])) * SCALE;
#pragma unroll
                for (int msk = 1; msk < 16; msk <<= 1)
                    t0 = fmaxf(t0, __shfl_xor(t0, msk));
                float mnew = fmaxf(mrun[idx], t0);
                float fac = expf(mrun[idx] - mnew);
                float ps = 0.f;
#pragma unroll
                for (int nj = 0; nj < 4; ++nj) {
                    float p = expf(s[mi][nj][i] * SCALE - mnew);
                    ps += p;
                    Pl[wv][mi*16 + lg*4 + i][nj*16 + lr] = f2bf(p);
                }
#pragma unroll
                for (int msk = 1; msk < 16; msk <<= 1)
                    ps += __shfl_xor(ps, msk);
                lrun[idx] = lrun[idx] * fac + ps;
                mrun[idx] = mnew;
#pragma unroll
                for (int nd = 0; nd < 4; ++nd) oacc[mi][nd][i] *= fac;
            }
        }
        __syncthreads();   // P visible to own wave's ds_reads + keeps waves in lockstep

        // O += P * V  (A = P[64 rows][64 kv], Bt = Vt[64 d][64 kv])
#pragma unroll
        for (int ks = 0; ks < 2; ++ks) {
            short8 pa[4], vb[4];
#pragma unroll
            for (int mi = 0; mi < 4; ++mi)
                pa[mi] = *reinterpret_cast<const short8*>(&Pl[wv][mi*16 + lr][ks*32 + lk]);
#pragma unroll
            for (int nd = 0; nd < 4; ++nd)
                vb[nd] = *reinterpret_cast<const short8*>(&Vl[nd*16 + lr][ks*32 + lk]);
#pragma unroll
            for (int mi = 0; mi < 4; ++mi)
#pragma unroll
                for (int nd = 0; nd < 4; ++nd)
                    oacc[mi][nd] = __builtin_amdgcn_mfma_f32_16x16x32_bf16(pa[mi], vb[nd], oacc[mi][nd], 0, 0, 0);
        }
    }

    // epilogue: out rows = b*N + q, cols = h*64 + d
#pragma unroll
    for (int mi = 0; mi < 4; ++mi)
#pragma unroll
        for (int nd = 0; nd < 4; ++nd)
#pragma unroll
            for (int i = 0; i < 4; ++i) {
                int r = b*Nseq + q0 + mi*16 + lg*4 + i;
                int c = h*64 + nd*16 + lr;
                attn_o[(size_t)r * Dmod + c] = f2bf(oacc[mi][nd][i] / lrun[mi*4 + i]);
            }
}

// ---------------- launch ----------------
extern "C" void kernel_launch(void* const* d_in, const int* in_sizes, int n_in,
                              void* d_out, int out_size, void* d_ws, size_t ws_size,
                              hipStream_t stream) {
    const float* x      = (const float*)d_in[0];
    const float* w_qkv  = (const float*)d_in[1];
    const float* w_proj = (const float*)d_in[2];
    const float* b_proj = (const float*)d_in[3];
    float* out = (float*)d_out;
    char* ws = (char*)d_ws;

    // workspace layout (bytes)
    unsigned short* qkv    = (unsigned short*)(ws);               // 8192*3072*2 = 50331648
    unsigned short* vT     = (unsigned short*)(ws + 50331648);    // 64*64*2048*2 = 16777216
    unsigned short* xb     = (unsigned short*)(ws + 67108864);    // 16777216 (reused as attn_o)
    unsigned short* attn_o = xb;                                  // xb dead after GEMM1
    unsigned short* wqkvT  = (unsigned short*)(ws + 83886080);    // 6291456
    unsigned short* wprojT = (unsigned short*)(ws + 90177536);    // 2097152

    cast_x_kernel<<<2048, 256, 0, stream>>>(x, xb, (Bdim*Nseq*Dmod)/4);
    transpose_cast_kernel<<<dim3(3072/32, 1024/32), dim3(32, 8), 0, stream>>>(w_qkv, wqkvT, 1024, 3072);
    transpose_cast_kernel<<<dim3(1024/32, 1024/32), dim3(32, 8), 0, stream>>>(w_proj, wprojT, 1024, 1024);
    // qkv = x @ w_qkv  -> bf16 [8192, 3072]
    gemm_bt_kernel<true, false><<<dim3(3072/128, 8192/128), 256, 0, stream>>>(
        xb, wqkvT, qkv, nullptr, Bdim*Nseq, 3*Dmod, Dmod);
    transpose_v_kernel<<<dim3(Nseq/64, Bdim*Hn), 256, 0, stream>>>(qkv, vT);
    attn_kernel<<<dim3(Nseq/256, Bdim*Hn), 256, 0, stream>>>(qkv, vT, attn_o);
    // out = attn @ w_proj + b_proj -> fp32
    gemm_bt_kernel<false, true><<<dim3(1024/128, 8192/128), 256, 0, stream>>>(
        attn_o, wprojT, out, b_proj, Bdim*Nseq, Dmod, Dmod);
}

// Round 3
// 255.556 us; speedup vs baseline: 2.4654x; 2.4654x over previous
//
#include <hip/hip_runtime.h>
#include <stdint.h>

// Problem constants
#define Bdim 4
#define Nseq 2048
#define Dmod 1024
#define Hn   16
#define HD   64
#define SCALE 0.03125f   // D^-0.5 = 1/32
#define L2E   1.44269504089f

typedef __attribute__((ext_vector_type(8))) short short8;
typedef __attribute__((ext_vector_type(8))) unsigned short ushort8;
typedef __attribute__((ext_vector_type(4))) float f32x4;
typedef __attribute__((ext_vector_type(16))) float f32x16;

static __device__ __forceinline__ unsigned short f2bf(float f) {
    union { float f; uint32_t u; } v; v.f = f;
    uint32_t r = (v.u + 0x7FFFu + ((v.u >> 16) & 1u)) >> 16;
    return (unsigned short)r;
}

// ---------------- cast x (fp32 -> bf16), vectorized ----------------
__global__ __launch_bounds__(256) void cast_x_kernel(const float* __restrict__ in,
                                                     unsigned short* __restrict__ out, int n4) {
    int i = blockIdx.x * blockDim.x + threadIdx.x;
    int stride = gridDim.x * blockDim.x;
    for (; i < n4; i += stride) {
        float4 v = reinterpret_cast<const float4*>(in)[i];
        ushort4 o;
        o.x = f2bf(v.x); o.y = f2bf(v.y); o.z = f2bf(v.z); o.w = f2bf(v.w);
        reinterpret_cast<ushort4*>(out)[i] = o;
    }
}

// ---------------- transpose + cast weights: out[c][r] = in[r][c] ----------------
__global__ void transpose_cast_kernel(const float* __restrict__ in,
                                      unsigned short* __restrict__ out, int R, int C) {
    __shared__ unsigned short t[32][33];
    int c0 = blockIdx.x * 32, r0 = blockIdx.y * 32;
    int tx = threadIdx.x, ty = threadIdx.y;
#pragma unroll
    for (int i = 0; i < 4; ++i)
        t[ty + i*8][tx] = f2bf(in[(size_t)(r0 + ty + i*8) * C + c0 + tx]);
    __syncthreads();
#pragma unroll
    for (int i = 0; i < 4; ++i)
        out[(size_t)(c0 + ty + i*8) * R + r0 + tx] = t[tx][ty + i*8];
}

// ---------------- bf16 GEMM: C[M,N] = A[M,K] * Bt[N,K]^T (+bias) ----------------
template<bool OUT_BF16, bool BIAS>
__global__ __launch_bounds__(256) void gemm_bt_kernel(const unsigned short* __restrict__ A,
                                                      const unsigned short* __restrict__ Bt,
                                                      void* __restrict__ Cv,
                                                      const float* __restrict__ bias,
                                                      int M, int N, int K) {
    __shared__ unsigned short Al[128][72];
    __shared__ unsigned short Bl[128][72];
    int tid = threadIdx.x;
    int lane = tid & 63, wv = tid >> 6;
    int wr = (wv >> 1) * 64, wc = (wv & 1) * 64;
    int lr = lane & 15, lg = lane >> 4;
    int lk = lg * 8;
    int m0 = blockIdx.y * 128, n0 = blockIdx.x * 128;
    int srow = tid >> 1, scol = (tid & 1) * 32;

    f32x4 acc[4][4];
#pragma unroll
    for (int i = 0; i < 4; ++i)
#pragma unroll
        for (int j = 0; j < 4; ++j) acc[i][j] = (f32x4)0.f;

    for (int k0 = 0; k0 < K; k0 += 64) {
        __syncthreads();
        const ushort8* ag = reinterpret_cast<const ushort8*>(A + (size_t)(m0 + srow) * K + k0 + scol);
        const ushort8* bg = reinterpret_cast<const ushort8*>(Bt + (size_t)(n0 + srow) * K + k0 + scol);
#pragma unroll
        for (int j = 0; j < 4; ++j) {
            *reinterpret_cast<ushort8*>(&Al[srow][scol + j*8]) = ag[j];
            *reinterpret_cast<ushort8*>(&Bl[srow][scol + j*8]) = bg[j];
        }
        __syncthreads();
#pragma unroll
        for (int ks = 0; ks < 2; ++ks) {
            short8 a[4], b[4];
#pragma unroll
            for (int mi = 0; mi < 4; ++mi)
                a[mi] = *reinterpret_cast<const short8*>(&Al[wr + mi*16 + lr][ks*32 + lk]);
#pragma unroll
            for (int nj = 0; nj < 4; ++nj)
                b[nj] = *reinterpret_cast<const short8*>(&Bl[wc + nj*16 + lr][ks*32 + lk]);
#pragma unroll
            for (int mi = 0; mi < 4; ++mi)
#pragma unroll
                for (int nj = 0; nj < 4; ++nj)
                    acc[mi][nj] = __builtin_amdgcn_mfma_f32_16x16x32_bf16(a[mi], b[nj], acc[mi][nj], 0, 0, 0);
        }
    }
#pragma unroll
    for (int mi = 0; mi < 4; ++mi) {
#pragma unroll
        for (int nj = 0; nj < 4; ++nj) {
            int r = m0 + wr + mi*16 + lg*4;
            int c = n0 + wc + nj*16 + lr;
            float bv = BIAS ? bias[c] : 0.f;
#pragma unroll
            for (int i = 0; i < 4; ++i) {
                float v = acc[mi][nj][i] + bv;
                if (OUT_BF16)
                    reinterpret_cast<unsigned short*>(Cv)[(size_t)(r + i) * N + c] = f2bf(v);
                else
                    reinterpret_cast<float*>(Cv)[(size_t)(r + i) * N + c] = v;
            }
        }
    }
}

// ---------------- vT[bh][d][j] = qkv[b*N + j][2048 + h*64 + d] ----------------
__global__ __launch_bounds__(256) void transpose_v_kernel(const unsigned short* __restrict__ qkv,
                                                          unsigned short* __restrict__ vT) {
    __shared__ unsigned short t[64][68];
    int bh = blockIdx.y, b = bh >> 4, h = bh & 15;
    int j0 = blockIdx.x * 64;
    int tid = threadIdx.x;
#pragma unroll
    for (int p = 0; p < 4; ++p) {
        int e = p * 256 + tid;
        int jj = e >> 4;
        int d4 = (e & 15) * 4;
        const unsigned short* src = qkv + (size_t)(b*Nseq + j0 + jj) * 3072 + 2048 + h*64 + d4;
        ushort4 v = *reinterpret_cast<const ushort4*>(src);
        *reinterpret_cast<ushort4*>(&t[jj][d4]) = v;
    }
    __syncthreads();
#pragma unroll
    for (int p = 0; p < 4; ++p) {
        int e = p * 256 + tid;
        int d = e >> 4;
        int j4 = (e & 15) * 4;
        ushort4 v;
        v.x = t[j4 + 0][d]; v.y = t[j4 + 1][d]; v.z = t[j4 + 2][d]; v.w = t[j4 + 3][d];
        *reinterpret_cast<ushort4*>(vT + ((size_t)bh * 64 + d) * Nseq + j0 + j4) = v;
    }
}

// ---------------- flash attention, swapped 32x32 MFMA, per-lane softmax, P via LDS ----------------
// 4 waves/block, 32 q rows/wave (block = 128 q), KV tile 64.
// S^T = mfma(K, Q): lane owns q = lane&31; kv(reg) = crow(reg,hi) = (reg&3)+8*(reg>>2)+4*hi.
// P staged to per-wave LDS tile [32 q][64 kv] (XOR-swizzled), read back as PV's B-operand
// with the SAME assumed k-map as the V^T A-operand -> k-map errors cancel.
// O^T = mfma(V^T, P): lane owns q = lane&31; d(reg) = db*32 + crow(reg,hi).
__global__ __launch_bounds__(256) void attn_kernel(const unsigned short* __restrict__ qkv,
                                                   const unsigned short* __restrict__ vT,
                                                   unsigned short* __restrict__ attn_o) {
    __shared__ unsigned short Kl[64 * 64];
    __shared__ unsigned short Vl[64 * 64];
    __shared__ unsigned short Pl[4 * 32 * 64];   // per-wave 32x64 P tile

    // bijective XCD-chunked swizzle: 1024 blocks = 8 XCDs x 128
    int w = blockIdx.x;
    int lid = (w & 7) * 128 + (w >> 3);
    int bh = lid >> 4, qb = lid & 15;
    int b = bh >> 4, h = bh & 15;

    int tid = threadIdx.x, lane = tid & 63, wv = tid >> 6;
    int lr = lane & 31, hi = lane >> 5;
    int q0 = qb * 128 + wv * 32;

    // Q b-frags (held all kernel): qf[ks] = Q[q0+lr][d = ks*16 + hi*8 + j]
    short8 qf[4];
    {
        const unsigned short* qrow = qkv + (size_t)(b * Nseq + q0 + lr) * 3072 + h * 64 + hi * 8;
#pragma unroll
        for (int ks = 0; ks < 4; ++ks)
            qf[ks] = *reinterpret_cast<const short8*>(qrow + ks * 16);
    }

    float mrun = -1e30f, lrun = 0.f;
    f32x16 oacc0 = (f32x16)0.f, oacc1 = (f32x16)0.f;

    // staging: thread t covers tile row sr, byte cols [sc, sc+32)
    int sr = tid >> 2;
    int sc = (tid & 3) * 32;
    const unsigned short* kg = qkv + (size_t)(b * Nseq + sr) * 3072 + 1024 + h * 64 + sc / 2;
    const unsigned short* vg = vT + ((size_t)(bh * 64 + sr)) * Nseq + sc / 2;
    int swz0 = sr * 128 + ((sc) ^ ((sr & 7) << 4));
    int swz1 = sr * 128 + ((sc + 16) ^ ((sr & 7) << 4));
    int rswz = (lr & 7) << 4;            // row-dependent XOR (rows lr and lr+32 share lr&7)
    char* PlW = (char*)Pl + wv * 4096 + lr * 128;   // this lane's q-row in the wave's P tile

    for (int jt = 0; jt < Nseq; jt += 64) {
        ushort8 k0 = *reinterpret_cast<const ushort8*>(kg + (size_t)jt * 3072);
        ushort8 k1 = *reinterpret_cast<const ushort8*>(kg + (size_t)jt * 3072 + 8);
        ushort8 v0 = *reinterpret_cast<const ushort8*>(vg + jt);
        ushort8 v1 = *reinterpret_cast<const ushort8*>(vg + jt + 8);
        __syncthreads();   // previous tile's K/V LDS reads complete
        *reinterpret_cast<ushort8*>((char*)Kl + swz0) = k0;
        *reinterpret_cast<ushort8*>((char*)Kl + swz1) = k1;
        *reinterpret_cast<ushort8*>((char*)Vl + swz0) = v0;
        *reinterpret_cast<ushort8*>((char*)Vl + swz1) = v1;
        __syncthreads();

        // ---- S^T = K · Q^T ----
        f32x16 s0 = (f32x16)0.f, s1 = (f32x16)0.f;
#pragma unroll
        for (int ks = 0; ks < 4; ++ks) {
            int cb = ks * 32 + hi * 16;
            short8 kf0 = *reinterpret_cast<const short8*>((char*)Kl + lr * 128 + (cb ^ rswz));
            short8 kf1 = *reinterpret_cast<const short8*>((char*)Kl + (lr + 32) * 128 + (cb ^ rswz));
            s0 = __builtin_amdgcn_mfma_f32_32x32x16_bf16(kf0, qf[ks], s0, 0, 0, 0);
            s1 = __builtin_amdgcn_mfma_f32_32x32x16_bf16(kf1, qf[ks], s1, 0, 0, 0);
        }

        // ---- online softmax, per-lane (lane pair l, l^32 share q=lr and split the 64 kv) ----
        float mloc = s0[0];
#pragma unroll
        for (int i = 1; i < 16; ++i) mloc = fmaxf(mloc, s0[i]);
#pragma unroll
        for (int i = 0; i < 16; ++i) mloc = fmaxf(mloc, s1[i]);
        mloc = fmaxf(mloc, __shfl_xor(mloc, 32));
        float mnew = fmaxf(mrun, mloc * SCALE);
        float fac = __builtin_amdgcn_exp2f((mrun - mnew) * L2E);
        const float c1 = SCALE * L2E;
        float c0 = -mnew * L2E;
        float ps = 0.f;
        float p0[16], p1[16];
#pragma unroll
        for (int i = 0; i < 16; ++i) { p0[i] = __builtin_amdgcn_exp2f(fmaf(s0[i], c1, c0)); ps += p0[i]; }
#pragma unroll
        for (int i = 0; i < 16; ++i) { p1[i] = __builtin_amdgcn_exp2f(fmaf(s1[i], c1, c0)); ps += p1[i]; }
        ps += __shfl_xor(ps, 32);
        lrun = lrun * fac + ps;
        mrun = mnew;
#pragma unroll
        for (int i = 0; i < 16; ++i) { oacc0[i] *= fac; oacc1[i] *= fac; }

        // ---- pack P pairs (kv-consecutive: regs 4t..4t+3 -> kv 8t+4hi+{0..3}) and
        //      write to own q-row of the wave's P tile, swizzled b64 stores ----
        uint32_t W[16];
#pragma unroll
        for (int m = 0; m < 8; ++m)
            W[m] = (uint32_t)f2bf(p0[2*m]) | ((uint32_t)f2bf(p0[2*m+1]) << 16);
#pragma unroll
        for (int m = 0; m < 8; ++m)
            W[8+m] = (uint32_t)f2bf(p1[2*m]) | ((uint32_t)f2bf(p1[2*m+1]) << 16);
#pragma unroll
        for (int t = 0; t < 8; ++t) {
            uint64_t val = (uint64_t)W[2*t] | ((uint64_t)W[2*t+1] << 32);
            *reinterpret_cast<uint64_t*>(PlW + ((16*t + 8*hi) ^ rswz)) = val;
        }

        // ---- O^T += V^T · P : both operands read from LDS with the same assumed k-map ----
#pragma unroll
        for (int ks4 = 0; ks4 < 4; ++ks4) {
            int cb = ks4 * 32 + hi * 16;
            short8 pf  = *reinterpret_cast<const short8*>(PlW + (cb ^ rswz));
            short8 vf0 = *reinterpret_cast<const short8*>((char*)Vl + lr * 128 + (cb ^ rswz));
            short8 vf1 = *reinterpret_cast<const short8*>((char*)Vl + (lr + 32) * 128 + (cb ^ rswz));
            oacc0 = __builtin_amdgcn_mfma_f32_32x32x16_bf16(vf0, pf, oacc0, 0, 0, 0);
            oacc1 = __builtin_amdgcn_mfma_f32_32x32x16_bf16(vf1, pf, oacc1, 0, 0, 0);
        }
    }

    // ---- epilogue: O^T[d][q] -> attn_o[b*N + q][h*64 + d], lane owns q = lr ----
    float inv = 1.f / lrun;
    unsigned short* orow = attn_o + (size_t)(b * Nseq + q0 + lr) * Dmod + h * 64;
#pragma unroll
    for (int db = 0; db < 2; ++db)
#pragma unroll
        for (int g = 0; g < 4; ++g) {
            ushort4 o4;
            float v0 = (db ? oacc1[4*g+0] : oacc0[4*g+0]) * inv;
            float v1 = (db ? oacc1[4*g+1] : oacc0[4*g+1]) * inv;
            float v2 = (db ? oacc1[4*g+2] : oacc0[4*g+2]) * inv;
            float v3 = (db ? oacc1[4*g+3] : oacc0[4*g+3]) * inv;
            o4.x = f2bf(v0); o4.y = f2bf(v1); o4.z = f2bf(v2); o4.w = f2bf(v3);
            int d = db * 32 + 8 * g + 4 * hi;
            *reinterpret_cast<ushort4*>(orow + d) = o4;
        }
}

// ---------------- launch ----------------
extern "C" void kernel_launch(void* const* d_in, const int* in_sizes, int n_in,
                              void* d_out, int out_size, void* d_ws, size_t ws_size,
                              hipStream_t stream) {
    const float* x      = (const float*)d_in[0];
    const float* w_qkv  = (const float*)d_in[1];
    const float* w_proj = (const float*)d_in[2];
    const float* b_proj = (const float*)d_in[3];
    float* out = (float*)d_out;
    char* ws = (char*)d_ws;

    unsigned short* qkv    = (unsigned short*)(ws);               // 50331648 B
    unsigned short* vT     = (unsigned short*)(ws + 50331648);    // 16777216 B
    unsigned short* xb     = (unsigned short*)(ws + 67108864);    // 16777216 B (reused as attn_o)
    unsigned short* attn_o = xb;
    unsigned short* wqkvT  = (unsigned short*)(ws + 83886080);    // 6291456 B
    unsigned short* wprojT = (unsigned short*)(ws + 90177536);    // 2097152 B

    cast_x_kernel<<<2048, 256, 0, stream>>>(x, xb, (Bdim*Nseq*Dmod)/4);
    transpose_cast_kernel<<<dim3(3072/32, 1024/32), dim3(32, 8), 0, stream>>>(w_qkv, wqkvT, 1024, 3072);
    transpose_cast_kernel<<<dim3(1024/32, 1024/32), dim3(32, 8), 0, stream>>>(w_proj, wprojT, 1024, 1024);
    gemm_bt_kernel<true, false><<<dim3(3072/128, 8192/128), 256, 0, stream>>>(
        xb, wqkvT, qkv, nullptr, Bdim*Nseq, 3*Dmod, Dmod);
    transpose_v_kernel<<<dim3(Nseq/64, Bdim*Hn), 256, 0, stream>>>(qkv, vT);
    attn_kernel<<<1024, 256, 0, stream>>>(qkv, vT, attn_o);
    gemm_bt_kernel<false, true><<<dim3(1024/128, 8192/128), 256, 0, stream>>>(
        attn_o, wprojT, out, b_proj, Bdim*Nseq, Dmod, Dmod);
}

// Round 4
// 250.934 us; speedup vs baseline: 2.5108x; 1.0184x over previous
//
#include <hip/hip_runtime.h>
#include <stdint.h>

// Problem constants
#define Bdim 4
#define Nseq 2048
#define Dmod 1024
#define Hn   16
#define HD   64
#define SCALE 0.03125f   // D^-0.5 = 1/32
#define L2E   1.44269504089f

typedef __attribute__((ext_vector_type(8))) short short8;
typedef __attribute__((ext_vector_type(8))) unsigned short ushort8;
typedef __attribute__((ext_vector_type(4))) float f32x4;
typedef __attribute__((ext_vector_type(16))) float f32x16;

typedef __attribute__((address_space(3))) uint32_t lds_u32;
typedef __attribute__((address_space(1))) const uint32_t glob_u32;

static __device__ __forceinline__ void gload_lds16(const unsigned short* g, unsigned short* l) {
    __builtin_amdgcn_global_load_lds((glob_u32*)(const void*)g, (lds_u32*)(void*)l, 16, 0, 0);
}

static __device__ __forceinline__ unsigned short f2bf(float f) {
    union { float f; uint32_t u; } v; v.f = f;
    uint32_t r = (v.u + 0x7FFFu + ((v.u >> 16) & 1u)) >> 16;
    return (unsigned short)r;
}

// ---------------- cast x (fp32 -> bf16), vectorized ----------------
__global__ __launch_bounds__(256) void cast_x_kernel(const float* __restrict__ in,
                                                     unsigned short* __restrict__ out, int n4) {
    int i = blockIdx.x * blockDim.x + threadIdx.x;
    int stride = gridDim.x * blockDim.x;
    for (; i < n4; i += stride) {
        float4 v = reinterpret_cast<const float4*>(in)[i];
        ushort4 o;
        o.x = f2bf(v.x); o.y = f2bf(v.y); o.z = f2bf(v.z); o.w = f2bf(v.w);
        reinterpret_cast<ushort4*>(out)[i] = o;
    }
}

// ---------------- transpose + cast weights: out[c][r] = in[r][c] ----------------
__global__ void transpose_cast_kernel(const float* __restrict__ in,
                                      unsigned short* __restrict__ out, int R, int C) {
    __shared__ unsigned short t[32][33];
    int c0 = blockIdx.x * 32, r0 = blockIdx.y * 32;
    int tx = threadIdx.x, ty = threadIdx.y;
#pragma unroll
    for (int i = 0; i < 4; ++i)
        t[ty + i*8][tx] = f2bf(in[(size_t)(r0 + ty + i*8) * C + c0 + tx]);
    __syncthreads();
#pragma unroll
    for (int i = 0; i < 4; ++i)
        out[(size_t)(c0 + ty + i*8) * R + r0 + tx] = t[tx][ty + i*8];
}

// ---------------- bf16 GEMM (m97 structure): C[M,N] = A[M,K] * Bt[N,K]^T (+bias) ----------------
// 128x128 tile, BK=64, 4 waves (2x2 of 64x64), linear LDS + global_load_lds width-16.
template<bool OUT_BF16, bool BIAS>
__global__ __launch_bounds__(256) void gemm_bt_kernel(const unsigned short* __restrict__ A,
                                                      const unsigned short* __restrict__ Bt,
                                                      void* __restrict__ Cv,
                                                      const float* __restrict__ bias,
                                                      int M, int N, int K) {
    __shared__ unsigned short Al[128 * 64];   // linear: row stride 64 elem (128 B)
    __shared__ unsigned short Bl[128 * 64];
    int tid = threadIdx.x;
    int lane = tid & 63, wv = tid >> 6;
    int wr = (wv >> 1) * 64, wc = (wv & 1) * 64;
    int lr = lane & 15, lg = lane >> 4, lk = lg * 8;
    int m0 = blockIdx.y * 128, n0 = blockIdx.x * 128;

    // staging map: wave wv, iter i covers LDS bytes [i*4096 + wv*1024 + lane*16)
    // -> row = i*32 + wv*8 + (lane>>3), col elements = (lane&7)*8
    int srow = wv * 8 + (lane >> 3);
    int scol = (lane & 7) * 8;
    const unsigned short* ag = A  + (size_t)(m0 + srow) * K + scol;
    const unsigned short* bg = Bt + (size_t)(n0 + srow) * K + scol;
    unsigned short* la = Al + wv * 512;   // wv*1024 B
    unsigned short* lb = Bl + wv * 512;

    f32x4 acc[4][4];
#pragma unroll
    for (int i = 0; i < 4; ++i)
#pragma unroll
        for (int j = 0; j < 4; ++j) acc[i][j] = (f32x4)0.f;

    for (int k0 = 0; k0 < K; k0 += 64) {
        __syncthreads();
#pragma unroll
        for (int i = 0; i < 4; ++i) {
            gload_lds16(ag + (size_t)i * 32 * K + k0, la + i * 2048);
            gload_lds16(bg + (size_t)i * 32 * K + k0, lb + i * 2048);
        }
        __syncthreads();   // compiler drains vmcnt before barrier
#pragma unroll
        for (int ks = 0; ks < 2; ++ks) {
            short8 a[4], b[4];
#pragma unroll
            for (int mi = 0; mi < 4; ++mi)
                a[mi] = *reinterpret_cast<const short8*>(Al + (wr + mi*16 + lr) * 64 + ks*32 + lk);
#pragma unroll
            for (int nj = 0; nj < 4; ++nj)
                b[nj] = *reinterpret_cast<const short8*>(Bl + (wc + nj*16 + lr) * 64 + ks*32 + lk);
#pragma unroll
            for (int mi = 0; mi < 4; ++mi)
#pragma unroll
                for (int nj = 0; nj < 4; ++nj)
                    acc[mi][nj] = __builtin_amdgcn_mfma_f32_16x16x32_bf16(a[mi], b[nj], acc[mi][nj], 0, 0, 0);
        }
    }
#pragma unroll
    for (int mi = 0; mi < 4; ++mi) {
#pragma unroll
        for (int nj = 0; nj < 4; ++nj) {
            int r = m0 + wr + mi*16 + lg*4;
            int c = n0 + wc + nj*16 + lr;
            float bv = BIAS ? bias[c] : 0.f;
#pragma unroll
            for (int i = 0; i < 4; ++i) {
                float v = acc[mi][nj][i] + bv;
                if (OUT_BF16)
                    reinterpret_cast<unsigned short*>(Cv)[(size_t)(r + i) * N + c] = f2bf(v);
                else
                    reinterpret_cast<float*>(Cv)[(size_t)(r + i) * N + c] = v;
            }
        }
    }
}

// ---------------- vT[bh][d][j] = qkv[b*N + j][2048 + h*64 + d] ----------------
__global__ __launch_bounds__(256) void transpose_v_kernel(const unsigned short* __restrict__ qkv,
                                                          unsigned short* __restrict__ vT) {
    __shared__ unsigned short t[64][68];
    int bh = blockIdx.y, b = bh >> 4, h = bh & 15;
    int j0 = blockIdx.x * 64;
    int tid = threadIdx.x;
#pragma unroll
    for (int p = 0; p < 4; ++p) {
        int e = p * 256 + tid;
        int jj = e >> 4;
        int d4 = (e & 15) * 4;
        const unsigned short* src = qkv + (size_t)(b*Nseq + j0 + jj) * 3072 + 2048 + h*64 + d4;
        ushort4 v = *reinterpret_cast<const ushort4*>(src);
        *reinterpret_cast<ushort4*>(&t[jj][d4]) = v;
    }
    __syncthreads();
#pragma unroll
    for (int p = 0; p < 4; ++p) {
        int e = p * 256 + tid;
        int d = e >> 4;
        int j4 = (e & 15) * 4;
        ushort4 v;
        v.x = t[j4 + 0][d]; v.y = t[j4 + 1][d]; v.z = t[j4 + 2][d]; v.w = t[j4 + 3][d];
        *reinterpret_cast<ushort4*>(vT + ((size_t)bh * 64 + d) * Nseq + j0 + j4) = v;
    }
}

// ---------------- flash attention, swapped 32x32 MFMA, per-lane softmax, P via LDS ----------------
// + T14 async staging (next-tile loads issued under compute), T5 setprio, cvt_pk pack, reduce trees.
__global__ __launch_bounds__(256) void attn_kernel(const unsigned short* __restrict__ qkv,
                                                   const unsigned short* __restrict__ vT,
                                                   unsigned short* __restrict__ attn_o) {
    __shared__ unsigned short Kl[64 * 64];
    __shared__ unsigned short Vl[64 * 64];
    __shared__ unsigned short Pl[4 * 32 * 64];   // per-wave 32x64 P tile

    // bijective XCD-chunked swizzle: 1024 blocks = 8 XCDs x 128
    int w = blockIdx.x;
    int lid = (w & 7) * 128 + (w >> 3);
    int bh = lid >> 4, qb = lid & 15;
    int b = bh >> 4, h = bh & 15;

    int tid = threadIdx.x, lane = tid & 63, wv = tid >> 6;
    int lr = lane & 31, hi = lane >> 5;
    int q0 = qb * 128 + wv * 32;

    // Q b-frags (held all kernel): qf[ks] = Q[q0+lr][d = ks*16 + hi*8 + j]
    short8 qf[4];
    {
        const unsigned short* qrow = qkv + (size_t)(b * Nseq + q0 + lr) * 3072 + h * 64 + hi * 8;
#pragma unroll
        for (int ks = 0; ks < 4; ++ks)
            qf[ks] = *reinterpret_cast<const short8*>(qrow + ks * 16);
    }

    float mrun = -1e30f, lrun = 0.f;
    f32x16 oacc0 = (f32x16)0.f, oacc1 = (f32x16)0.f;

    // staging: thread t covers tile row sr, byte cols [sc, sc+32)
    int sr = tid >> 2;
    int sc = (tid & 3) * 32;
    const unsigned short* kg = qkv + (size_t)(b * Nseq + sr) * 3072 + 1024 + h * 64 + sc / 2;
    const unsigned short* vg = vT + ((size_t)(bh * 64 + sr)) * Nseq + sc / 2;
    int swz0 = sr * 128 + ((sc) ^ ((sr & 7) << 4));
    int swz1 = sr * 128 + ((sc + 16) ^ ((sr & 7) << 4));
    int rswz = (lr & 7) << 4;            // row-dependent XOR (rows lr and lr+32 share lr&7)
    char* PlW = (char*)Pl + wv * 4096 + lr * 128;

    // prologue: tile 0 staged to regs
    ushort8 k0r = *reinterpret_cast<const ushort8*>(kg);
    ushort8 k1r = *reinterpret_cast<const ushort8*>(kg + 8);
    ushort8 v0r = *reinterpret_cast<const ushort8*>(vg);
    ushort8 v1r = *reinterpret_cast<const ushort8*>(vg + 8);

    for (int jt = 0; jt < Nseq; jt += 64) {
        __syncthreads();   // previous tile's K/V LDS reads complete
        *reinterpret_cast<ushort8*>((char*)Kl + swz0) = k0r;
        *reinterpret_cast<ushort8*>((char*)Kl + swz1) = k1r;
        *reinterpret_cast<ushort8*>((char*)Vl + swz0) = v0r;
        *reinterpret_cast<ushort8*>((char*)Vl + swz1) = v1r;
        int jn = jt + 64;
        if (jn < Nseq) {   // issue next tile's loads; latency hides under compute
            k0r = *reinterpret_cast<const ushort8*>(kg + (size_t)jn * 3072);
            k1r = *reinterpret_cast<const ushort8*>(kg + (size_t)jn * 3072 + 8);
            v0r = *reinterpret_cast<const ushort8*>(vg + jn);
            v1r = *reinterpret_cast<const ushort8*>(vg + jn + 8);
        }
        __syncthreads();

        // ---- S^T = K · Q^T ----
        f32x16 s0 = (f32x16)0.f, s1 = (f32x16)0.f;
        __builtin_amdgcn_s_setprio(1);
#pragma unroll
        for (int ks = 0; ks < 4; ++ks) {
            int cb = ks * 32 + hi * 16;
            short8 kf0 = *reinterpret_cast<const short8*>((char*)Kl + lr * 128 + (cb ^ rswz));
            short8 kf1 = *reinterpret_cast<const short8*>((char*)Kl + (lr + 32) * 128 + (cb ^ rswz));
            s0 = __builtin_amdgcn_mfma_f32_32x32x16_bf16(kf0, qf[ks], s0, 0, 0, 0);
            s1 = __builtin_amdgcn_mfma_f32_32x32x16_bf16(kf1, qf[ks], s1, 0, 0, 0);
        }
        __builtin_amdgcn_s_setprio(0);

        // ---- online softmax, per-lane (lanes l, l^32 share q=lr, split 64 kv) ----
        float t[16];
#pragma unroll
        for (int i = 0; i < 16; ++i) t[i] = fmaxf(s0[i], s1[i]);
#pragma unroll
        for (int st = 8; st > 0; st >>= 1)
#pragma unroll
            for (int i = 0; i < st; ++i) t[i] = fmaxf(t[i], t[i + st]);
        float mloc = fmaxf(t[0], __shfl_xor(t[0], 32));
        float mnew = fmaxf(mrun, mloc * SCALE);
        float fac = __builtin_amdgcn_exp2f((mrun - mnew) * L2E);
        const float c1 = SCALE * L2E;
        float c0 = -mnew * L2E;
        float p0[16], p1[16];
#pragma unroll
        for (int i = 0; i < 16; ++i) p0[i] = __builtin_amdgcn_exp2f(fmaf(s0[i], c1, c0));
#pragma unroll
        for (int i = 0; i < 16; ++i) p1[i] = __builtin_amdgcn_exp2f(fmaf(s1[i], c1, c0));
        float a[16];
#pragma unroll
        for (int i = 0; i < 16; ++i) a[i] = p0[i] + p1[i];
#pragma unroll
        for (int st = 8; st > 0; st >>= 1)
#pragma unroll
            for (int i = 0; i < st; ++i) a[i] = a[i] + a[i + st];
        float ps = a[0] + __shfl_xor(a[0], 32);
        lrun = lrun * fac + ps;
        mrun = mnew;
#pragma unroll
        for (int i = 0; i < 16; ++i) { oacc0[i] *= fac; oacc1[i] *= fac; }

        // ---- pack P via cvt_pk (kv-consecutive pairs), write to own q-row, swizzled b64 ----
        uint32_t W[16];
#pragma unroll
        for (int m = 0; m < 8; ++m) {
            asm("v_cvt_pk_bf16_f32 %0, %1, %2" : "=v"(W[m])   : "v"(p0[2*m]), "v"(p0[2*m+1]));
            asm("v_cvt_pk_bf16_f32 %0, %1, %2" : "=v"(W[8+m]) : "v"(p1[2*m]), "v"(p1[2*m+1]));
        }
#pragma unroll
        for (int tt = 0; tt < 8; ++tt) {
            uint64_t val = (uint64_t)W[2*tt] | ((uint64_t)W[2*tt+1] << 32);
            *reinterpret_cast<uint64_t*>(PlW + ((16*tt + 8*hi) ^ rswz)) = val;
        }

        // ---- O^T += V^T · P : both operands via LDS with the same assumed k-map ----
        __builtin_amdgcn_s_setprio(1);
#pragma unroll
        for (int ks4 = 0; ks4 < 4; ++ks4) {
            int cb = ks4 * 32 + hi * 16;
            short8 pf  = *reinterpret_cast<const short8*>(PlW + (cb ^ rswz));
            short8 vf0 = *reinterpret_cast<const short8*>((char*)Vl + lr * 128 + (cb ^ rswz));
            short8 vf1 = *reinterpret_cast<const short8*>((char*)Vl + (lr + 32) * 128 + (cb ^ rswz));
            oacc0 = __builtin_amdgcn_mfma_f32_32x32x16_bf16(vf0, pf, oacc0, 0, 0, 0);
            oacc1 = __builtin_amdgcn_mfma_f32_32x32x16_bf16(vf1, pf, oacc1, 0, 0, 0);
        }
        __builtin_amdgcn_s_setprio(0);
    }

    // ---- epilogue: O^T[d][q] -> attn_o[b*N + q][h*64 + d], lane owns q = lr ----
    float inv = 1.f / lrun;
    unsigned short* orow = attn_o + (size_t)(b * Nseq + q0 + lr) * Dmod + h * 64;
#pragma unroll
    for (int db = 0; db < 2; ++db)
#pragma unroll
        for (int g = 0; g < 4; ++g) {
            ushort4 o4;
            float v0 = (db ? oacc1[4*g+0] : oacc0[4*g+0]) * inv;
            float v1 = (db ? oacc1[4*g+1] : oacc0[4*g+1]) * inv;
            float v2 = (db ? oacc1[4*g+2] : oacc0[4*g+2]) * inv;
            float v3 = (db ? oacc1[4*g+3] : oacc0[4*g+3]) * inv;
            o4.x = f2bf(v0); o4.y = f2bf(v1); o4.z = f2bf(v2); o4.w = f2bf(v3);
            int d = db * 32 + 8 * g + 4 * hi;
            *reinterpret_cast<ushort4*>(orow + d) = o4;
        }
}

// ---------------- launch ----------------
extern "C" void kernel_launch(void* const* d_in, const int* in_sizes, int n_in,
                              void* d_out, int out_size, void* d_ws, size_t ws_size,
                              hipStream_t stream) {
    const float* x      = (const float*)d_in[0];
    const float* w_qkv  = (const float*)d_in[1];
    const float* w_proj = (const float*)d_in[2];
    const float* b_proj = (const float*)d_in[3];
    float* out = (float*)d_out;
    char* ws = (char*)d_ws;

    unsigned short* qkv    = (unsigned short*)(ws);               // 50331648 B
    unsigned short* vT     = (unsigned short*)(ws + 50331648);    // 16777216 B
    unsigned short* xb     = (unsigned short*)(ws + 67108864);    // 16777216 B (reused as attn_o)
    unsigned short* attn_o = xb;
    unsigned short* wqkvT  = (unsigned short*)(ws + 83886080);    // 6291456 B
    unsigned short* wprojT = (unsigned short*)(ws + 90177536);    // 2097152 B

    cast_x_kernel<<<2048, 256, 0, stream>>>(x, xb, (Bdim*Nseq*Dmod)/4);
    transpose_cast_kernel<<<dim3(3072/32, 1024/32), dim3(32, 8), 0, stream>>>(w_qkv, wqkvT, 1024, 3072);
    transpose_cast_kernel<<<dim3(1024/32, 1024/32), dim3(32, 8), 0, stream>>>(w_proj, wprojT, 1024, 1024);
    gemm_bt_kernel<true, false><<<dim3(3072/128, 8192/128), 256, 0, stream>>>(
        xb, wqkvT, qkv, nullptr, Bdim*Nseq, 3*Dmod, Dmod);
    transpose_v_kernel<<<dim3(Nseq/64, Bdim*Hn), 256, 0, stream>>>(qkv, vT);
    attn_kernel<<<1024, 256, 0, stream>>>(qkv, vT, attn_o);
    gemm_bt_kernel<false, true><<<dim3(1024/128, 8192/128), 256, 0, stream>>>(
        attn_o, wprojT, out, b_proj, Bdim*Nseq, Dmod, Dmod);
}

// Round 5
// 224.473 us; speedup vs baseline: 2.8068x; 1.1179x over previous
//
#include <hip/hip_runtime.h>
#include <stdint.h>

// Problem constants
#define Bdim 4
#define Nseq 2048
#define Dmod 1024
#define Hn   16
#define HD   64
#define SCALE 0.03125f   // D^-0.5 = 1/32
#define L2E   1.44269504089f

typedef __attribute__((ext_vector_type(8))) short short8;
typedef __attribute__((ext_vector_type(8))) unsigned short ushort8;
typedef __attribute__((ext_vector_type(4))) float f32x4;
typedef __attribute__((ext_vector_type(16))) float f32x16;

typedef __attribute__((address_space(3))) uint32_t lds_u32;
typedef __attribute__((address_space(1))) const uint32_t glob_u32;

static __device__ __forceinline__ void gload_lds16(const unsigned short* g, unsigned short* l) {
    __builtin_amdgcn_global_load_lds((glob_u32*)(const void*)g, (lds_u32*)(void*)l, 16, 0, 0);
}

static __device__ __forceinline__ unsigned short f2bf(float f) {
    union { float f; uint32_t u; } v; v.f = f;
    uint32_t r = (v.u + 0x7FFFu + ((v.u >> 16) & 1u)) >> 16;
    return (unsigned short)r;
}

// ---------------- cast x (fp32 -> bf16), vectorized ----------------
__global__ __launch_bounds__(256) void cast_x_kernel(const float* __restrict__ in,
                                                     unsigned short* __restrict__ out, int n4) {
    int i = blockIdx.x * blockDim.x + threadIdx.x;
    int stride = gridDim.x * blockDim.x;
    for (; i < n4; i += stride) {
        float4 v = reinterpret_cast<const float4*>(in)[i];
        ushort4 o;
        o.x = f2bf(v.x); o.y = f2bf(v.y); o.z = f2bf(v.z); o.w = f2bf(v.w);
        reinterpret_cast<ushort4*>(out)[i] = o;
    }
}

// ---------------- transpose + cast weights: out[c][r] = in[r][c] ----------------
__global__ void transpose_cast_kernel(const float* __restrict__ in,
                                      unsigned short* __restrict__ out, int R, int C) {
    __shared__ unsigned short t[32][33];
    int c0 = blockIdx.x * 32, r0 = blockIdx.y * 32;
    int tx = threadIdx.x, ty = threadIdx.y;
#pragma unroll
    for (int i = 0; i < 4; ++i)
        t[ty + i*8][tx] = f2bf(in[(size_t)(r0 + ty + i*8) * C + c0 + tx]);
    __syncthreads();
#pragma unroll
    for (int i = 0; i < 4; ++i)
        out[(size_t)(c0 + ty + i*8) * R + r0 + tx] = t[tx][ty + i*8];
}

// ---------------- bf16 GEMM (m97 structure): C[M,N] = A[M,K] * Bt[N,K]^T (+bias) ----------------
template<bool OUT_BF16, bool BIAS>
__global__ __launch_bounds__(256) void gemm_bt_kernel(const unsigned short* __restrict__ A,
                                                      const unsigned short* __restrict__ Bt,
                                                      void* __restrict__ Cv,
                                                      const float* __restrict__ bias,
                                                      int M, int N, int K) {
    __shared__ unsigned short Al[128 * 64];   // linear: row stride 64 elem (128 B)
    __shared__ unsigned short Bl[128 * 64];
    int tid = threadIdx.x;
    int lane = tid & 63, wv = tid >> 6;
    int wr = (wv >> 1) * 64, wc = (wv & 1) * 64;
    int lr = lane & 15, lg = lane >> 4, lk = lg * 8;
    int m0 = blockIdx.y * 128, n0 = blockIdx.x * 128;

    int srow = wv * 8 + (lane >> 3);
    int scol = (lane & 7) * 8;
    const unsigned short* ag = A  + (size_t)(m0 + srow) * K + scol;
    const unsigned short* bg = Bt + (size_t)(n0 + srow) * K + scol;
    unsigned short* la = Al + wv * 512;
    unsigned short* lb = Bl + wv * 512;

    f32x4 acc[4][4];
#pragma unroll
    for (int i = 0; i < 4; ++i)
#pragma unroll
        for (int j = 0; j < 4; ++j) acc[i][j] = (f32x4)0.f;

    for (int k0 = 0; k0 < K; k0 += 64) {
        __syncthreads();
#pragma unroll
        for (int i = 0; i < 4; ++i) {
            gload_lds16(ag + (size_t)i * 32 * K + k0, la + i * 2048);
            gload_lds16(bg + (size_t)i * 32 * K + k0, lb + i * 2048);
        }
        __syncthreads();
#pragma unroll
        for (int ks = 0; ks < 2; ++ks) {
            short8 a[4], b[4];
#pragma unroll
            for (int mi = 0; mi < 4; ++mi)
                a[mi] = *reinterpret_cast<const short8*>(Al + (wr + mi*16 + lr) * 64 + ks*32 + lk);
#pragma unroll
            for (int nj = 0; nj < 4; ++nj)
                b[nj] = *reinterpret_cast<const short8*>(Bl + (wc + nj*16 + lr) * 64 + ks*32 + lk);
#pragma unroll
            for (int mi = 0; mi < 4; ++mi)
#pragma unroll
                for (int nj = 0; nj < 4; ++nj)
                    acc[mi][nj] = __builtin_amdgcn_mfma_f32_16x16x32_bf16(a[mi], b[nj], acc[mi][nj], 0, 0, 0);
        }
    }
#pragma unroll
    for (int mi = 0; mi < 4; ++mi) {
#pragma unroll
        for (int nj = 0; nj < 4; ++nj) {
            int r = m0 + wr + mi*16 + lg*4;
            int c = n0 + wc + nj*16 + lr;
            float bv = BIAS ? bias[c] : 0.f;
#pragma unroll
            for (int i = 0; i < 4; ++i) {
                float v = acc[mi][nj][i] + bv;
                if (OUT_BF16)
                    reinterpret_cast<unsigned short*>(Cv)[(size_t)(r + i) * N + c] = f2bf(v);
                else
                    reinterpret_cast<float*>(Cv)[(size_t)(r + i) * N + c] = v;
            }
        }
    }
}

// ---------------- vT[bh][d][j] = qkv[b*N + j][2048 + h*64 + d] ----------------
__global__ __launch_bounds__(256) void transpose_v_kernel(const unsigned short* __restrict__ qkv,
                                                          unsigned short* __restrict__ vT) {
    __shared__ unsigned short t[64][68];
    int bh = blockIdx.y, b = bh >> 4, h = bh & 15;
    int j0 = blockIdx.x * 64;
    int tid = threadIdx.x;
#pragma unroll
    for (int p = 0; p < 4; ++p) {
        int e = p * 256 + tid;
        int jj = e >> 4;
        int d4 = (e & 15) * 4;
        const unsigned short* src = qkv + (size_t)(b*Nseq + j0 + jj) * 3072 + 2048 + h*64 + d4;
        ushort4 v = *reinterpret_cast<const ushort4*>(src);
        *reinterpret_cast<ushort4*>(&t[jj][d4]) = v;
    }
    __syncthreads();
#pragma unroll
    for (int p = 0; p < 4; ++p) {
        int e = p * 256 + tid;
        int d = e >> 4;
        int j4 = (e & 15) * 4;
        ushort4 v;
        v.x = t[j4 + 0][d]; v.y = t[j4 + 1][d]; v.z = t[j4 + 2][d]; v.w = t[j4 + 3][d];
        *reinterpret_cast<ushort4*>(vT + ((size_t)bh * 64 + d) * Nseq + j0 + j4) = v;
    }
}

// ---------------- flash attention: 64 q/wave (2 subtiles), K/V frags reused, defer-max ----------------
// S^T = mfma(K, Q): lane owns q = q0 + sub*32 + (lane&31); kv(reg) = (reg&3)+8*(reg>>2)+4*hi (+32 for *1).
// P via per-wave LDS (k-map cancels); O^T = mfma(V^T, P).
__global__ __launch_bounds__(256, 2) void attn_kernel(const unsigned short* __restrict__ qkv,
                                                      const unsigned short* __restrict__ vT,
                                                      unsigned short* __restrict__ attn_o) {
    __shared__ unsigned short Kl[64 * 64];
    __shared__ unsigned short Vl[64 * 64];
    __shared__ unsigned short Pl[4 * 64 * 64];   // per-wave 64x64 P tile (A rows 0-31, B rows 32-63)

    // bijective XCD-chunked swizzle: 512 blocks = 8 XCDs x 64; 8 consecutive lids share one bh
    int w = blockIdx.x;
    int lid = (w & 7) * 64 + (w >> 3);
    int bh = lid >> 3, qb = lid & 7;
    int b = bh >> 4, h = bh & 15;

    int tid = threadIdx.x, lane = tid & 63, wv = tid >> 6;
    int lr = lane & 31, hi = lane >> 5;
    int q0 = qb * 256 + wv * 64;

    // Q b-frags for both subtiles: qf[ks] = Q[q][d = ks*16 + hi*8 + j]
    short8 qfA[4], qfB[4];
    {
        const unsigned short* qrowA = qkv + (size_t)(b * Nseq + q0 + lr) * 3072 + h * 64 + hi * 8;
        const unsigned short* qrowB = qrowA + (size_t)32 * 3072;
#pragma unroll
        for (int ks = 0; ks < 4; ++ks) {
            qfA[ks] = *reinterpret_cast<const short8*>(qrowA + ks * 16);
            qfB[ks] = *reinterpret_cast<const short8*>(qrowB + ks * 16);
        }
    }

    float mrunA = -1e30f, lrunA = 0.f, mrunB = -1e30f, lrunB = 0.f;
    f32x16 oA0 = (f32x16)0.f, oA1 = (f32x16)0.f, oB0 = (f32x16)0.f, oB1 = (f32x16)0.f;

    // staging: thread t covers tile row sr, byte cols [sc, sc+32)
    int sr = tid >> 2;
    int sc = (tid & 3) * 32;
    const unsigned short* kg = qkv + (size_t)(b * Nseq + sr) * 3072 + 1024 + h * 64 + sc / 2;
    const unsigned short* vg = vT + ((size_t)(bh * 64 + sr)) * Nseq + sc / 2;
    int swz0 = sr * 128 + ((sc) ^ ((sr & 7) << 4));
    int swz1 = sr * 128 + ((sc + 16) ^ ((sr & 7) << 4));
    int rswz = (lr & 7) << 4;            // rows lr and lr+32 share lr&7
    char* PlW = (char*)Pl + wv * 8192 + lr * 128;

    // prologue: tile 0 staged to regs
    ushort8 k0r = *reinterpret_cast<const ushort8*>(kg);
    ushort8 k1r = *reinterpret_cast<const ushort8*>(kg + 8);
    ushort8 v0r = *reinterpret_cast<const ushort8*>(vg);
    ushort8 v1r = *reinterpret_cast<const ushort8*>(vg + 8);

    for (int jt = 0; jt < Nseq; jt += 64) {
        __syncthreads();   // previous tile's K/V LDS reads complete
        *reinterpret_cast<ushort8*>((char*)Kl + swz0) = k0r;
        *reinterpret_cast<ushort8*>((char*)Kl + swz1) = k1r;
        *reinterpret_cast<ushort8*>((char*)Vl + swz0) = v0r;
        *reinterpret_cast<ushort8*>((char*)Vl + swz1) = v1r;
        int jn = jt + 64;
        if (jn < Nseq) {   // next tile's loads hide under compute
            k0r = *reinterpret_cast<const ushort8*>(kg + (size_t)jn * 3072);
            k1r = *reinterpret_cast<const ushort8*>(kg + (size_t)jn * 3072 + 8);
            v0r = *reinterpret_cast<const ushort8*>(vg + jn);
            v1r = *reinterpret_cast<const ushort8*>(vg + jn + 8);
        }
        __syncthreads();

        // ---- S^T = K · Q^T, K-frags read once, used by both subtiles ----
        f32x16 sA0 = (f32x16)0.f, sA1 = (f32x16)0.f, sB0 = (f32x16)0.f, sB1 = (f32x16)0.f;
        __builtin_amdgcn_s_setprio(1);
#pragma unroll
        for (int ks = 0; ks < 4; ++ks) {
            int cb = ks * 32 + hi * 16;
            short8 kf0 = *reinterpret_cast<const short8*>((char*)Kl + lr * 128 + (cb ^ rswz));
            short8 kf1 = *reinterpret_cast<const short8*>((char*)Kl + (lr + 32) * 128 + (cb ^ rswz));
            sA0 = __builtin_amdgcn_mfma_f32_32x32x16_bf16(kf0, qfA[ks], sA0, 0, 0, 0);
            sA1 = __builtin_amdgcn_mfma_f32_32x32x16_bf16(kf1, qfA[ks], sA1, 0, 0, 0);
            sB0 = __builtin_amdgcn_mfma_f32_32x32x16_bf16(kf0, qfB[ks], sB0, 0, 0, 0);
            sB1 = __builtin_amdgcn_mfma_f32_32x32x16_bf16(kf1, qfB[ks], sB1, 0, 0, 0);
        }
        __builtin_amdgcn_s_setprio(0);

        // ---- per-lane tile max for both subtiles ----
        float tA[16], tB[16];
#pragma unroll
        for (int i = 0; i < 16; ++i) { tA[i] = fmaxf(sA0[i], sA1[i]); tB[i] = fmaxf(sB0[i], sB1[i]); }
#pragma unroll
        for (int st = 8; st > 0; st >>= 1)
#pragma unroll
            for (int i = 0; i < st; ++i) { tA[i] = fmaxf(tA[i], tA[i + st]); tB[i] = fmaxf(tB[i], tB[i + st]); }
        float mlocA = fmaxf(tA[0], __shfl_xor(tA[0], 32)) * SCALE;
        float mlocB = fmaxf(tB[0], __shfl_xor(tB[0], 32)) * SCALE;

        // ---- defer-max (T13): rescale only when max grew > 8 ----
        if (!__all((mlocA <= mrunA + 8.f) && (mlocB <= mrunB + 8.f))) {
            float mnA = fmaxf(mrunA, mlocA);
            float fA = __builtin_amdgcn_exp2f((mrunA - mnA) * L2E);
            float mnB = fmaxf(mrunB, mlocB);
            float fB = __builtin_amdgcn_exp2f((mrunB - mnB) * L2E);
            lrunA *= fA; lrunB *= fB; mrunA = mnA; mrunB = mnB;
#pragma unroll
            for (int i = 0; i < 16; ++i) {
                oA0[i] *= fA; oA1[i] *= fA; oB0[i] *= fB; oB1[i] *= fB;
            }
        }

        // ---- P = exp2(s*c1 + c0) ----
        const float c1 = SCALE * L2E;
        float c0A = -mrunA * L2E, c0B = -mrunB * L2E;
        float pA0[16], pA1[16], pB0[16], pB1[16];
#pragma unroll
        for (int i = 0; i < 16; ++i) {
            pA0[i] = __builtin_amdgcn_exp2f(fmaf(sA0[i], c1, c0A));
            pA1[i] = __builtin_amdgcn_exp2f(fmaf(sA1[i], c1, c0A));
            pB0[i] = __builtin_amdgcn_exp2f(fmaf(sB0[i], c1, c0B));
            pB1[i] = __builtin_amdgcn_exp2f(fmaf(sB1[i], c1, c0B));
        }

        // ---- pack + write P (both subtiles), swizzled b64; then sum trees under LDS latency ----
        uint32_t WA[16], WB[16];
#pragma unroll
        for (int m = 0; m < 8; ++m) {
            asm("v_cvt_pk_bf16_f32 %0, %1, %2" : "=v"(WA[m])   : "v"(pA0[2*m]), "v"(pA0[2*m+1]));
            asm("v_cvt_pk_bf16_f32 %0, %1, %2" : "=v"(WA[8+m]) : "v"(pA1[2*m]), "v"(pA1[2*m+1]));
            asm("v_cvt_pk_bf16_f32 %0, %1, %2" : "=v"(WB[m])   : "v"(pB0[2*m]), "v"(pB0[2*m+1]));
            asm("v_cvt_pk_bf16_f32 %0, %1, %2" : "=v"(WB[8+m]) : "v"(pB1[2*m]), "v"(pB1[2*m+1]));
        }
#pragma unroll
        for (int tt = 0; tt < 8; ++tt) {
            uint64_t valA = (uint64_t)WA[2*tt] | ((uint64_t)WA[2*tt+1] << 32);
            uint64_t valB = (uint64_t)WB[2*tt] | ((uint64_t)WB[2*tt+1] << 32);
            int off = (16*tt + 8*hi) ^ rswz;
            *reinterpret_cast<uint64_t*>(PlW + off) = valA;
            *reinterpret_cast<uint64_t*>(PlW + 4096 + off) = valB;
        }

        float aA[16], aB[16];
#pragma unroll
        for (int i = 0; i < 16; ++i) { aA[i] = pA0[i] + pA1[i]; aB[i] = pB0[i] + pB1[i]; }
#pragma unroll
        for (int st = 8; st > 0; st >>= 1)
#pragma unroll
            for (int i = 0; i < st; ++i) { aA[i] += aA[i + st]; aB[i] += aB[i + st]; }
        lrunA += aA[0] + __shfl_xor(aA[0], 32);
        lrunB += aB[0] + __shfl_xor(aB[0], 32);

        // ---- O^T += V^T · P : V-frags read once, used by both subtiles ----
        __builtin_amdgcn_s_setprio(1);
#pragma unroll
        for (int ks4 = 0; ks4 < 4; ++ks4) {
            int cb = ks4 * 32 + hi * 16;
            short8 vf0 = *reinterpret_cast<const short8*>((char*)Vl + lr * 128 + (cb ^ rswz));
            short8 vf1 = *reinterpret_cast<const short8*>((char*)Vl + (lr + 32) * 128 + (cb ^ rswz));
            short8 pfA = *reinterpret_cast<const short8*>(PlW + (cb ^ rswz));
            short8 pfB = *reinterpret_cast<const short8*>(PlW + 4096 + (cb ^ rswz));
            oA0 = __builtin_amdgcn_mfma_f32_32x32x16_bf16(vf0, pfA, oA0, 0, 0, 0);
            oA1 = __builtin_amdgcn_mfma_f32_32x32x16_bf16(vf1, pfA, oA1, 0, 0, 0);
            oB0 = __builtin_amdgcn_mfma_f32_32x32x16_bf16(vf0, pfB, oB0, 0, 0, 0);
            oB1 = __builtin_amdgcn_mfma_f32_32x32x16_bf16(vf1, pfB, oB1, 0, 0, 0);
        }
        __builtin_amdgcn_s_setprio(0);
    }

    // ---- epilogue: O^T[d][q] -> attn_o[b*N + q][h*64 + d] ----
    float invA = 1.f / lrunA, invB = 1.f / lrunB;
    unsigned short* orowA = attn_o + (size_t)(b * Nseq + q0 + lr) * Dmod + h * 64;
    unsigned short* orowB = attn_o + (size_t)(b * Nseq + q0 + 32 + lr) * Dmod + h * 64;
#pragma unroll
    for (int db = 0; db < 2; ++db)
#pragma unroll
        for (int g = 0; g < 4; ++g) {
            int d = db * 32 + 8 * g + 4 * hi;
            ushort4 o4;
            o4.x = f2bf((db ? oA1[4*g+0] : oA0[4*g+0]) * invA);
            o4.y = f2bf((db ? oA1[4*g+1] : oA0[4*g+1]) * invA);
            o4.z = f2bf((db ? oA1[4*g+2] : oA0[4*g+2]) * invA);
            o4.w = f2bf((db ? oA1[4*g+3] : oA0[4*g+3]) * invA);
            *reinterpret_cast<ushort4*>(orowA + d) = o4;
            o4.x = f2bf((db ? oB1[4*g+0] : oB0[4*g+0]) * invB);
            o4.y = f2bf((db ? oB1[4*g+1] : oB0[4*g+1]) * invB);
            o4.z = f2bf((db ? oB1[4*g+2] : oB0[4*g+2]) * invB);
            o4.w = f2bf((db ? oB1[4*g+3] : oB0[4*g+3]) * invB);
            *reinterpret_cast<ushort4*>(orowB + d) = o4;
        }
}

// ---------------- launch ----------------
extern "C" void kernel_launch(void* const* d_in, const int* in_sizes, int n_in,
                              void* d_out, int out_size, void* d_ws, size_t ws_size,
                              hipStream_t stream) {
    const float* x      = (const float*)d_in[0];
    const float* w_qkv  = (const float*)d_in[1];
    const float* w_proj = (const float*)d_in[2];
    const float* b_proj = (const float*)d_in[3];
    float* out = (float*)d_out;
    char* ws = (char*)d_ws;

    unsigned short* qkv    = (unsigned short*)(ws);               // 50331648 B
    unsigned short* vT     = (unsigned short*)(ws + 50331648);    // 16777216 B
    unsigned short* xb     = (unsigned short*)(ws + 67108864);    // 16777216 B (reused as attn_o)
    unsigned short* attn_o = xb;
    unsigned short* wqkvT  = (unsigned short*)(ws + 83886080);    // 6291456 B
    unsigned short* wprojT = (unsigned short*)(ws + 90177536);    // 2097152 B

    cast_x_kernel<<<2048, 256, 0, stream>>>(x, xb, (Bdim*Nseq*Dmod)/4);
    transpose_cast_kernel<<<dim3(3072/32, 1024/32), dim3(32, 8), 0, stream>>>(w_qkv, wqkvT, 1024, 3072);
    transpose_cast_kernel<<<dim3(1024/32, 1024/32), dim3(32, 8), 0, stream>>>(w_proj, wprojT, 1024, 1024);
    gemm_bt_kernel<true, false><<<dim3(3072/128, 8192/128), 256, 0, stream>>>(
        xb, wqkvT, qkv, nullptr, Bdim*Nseq, 3*Dmod, Dmod);
    transpose_v_kernel<<<dim3(Nseq/64, Bdim*Hn), 256, 0, stream>>>(qkv, vT);
    attn_kernel<<<512, 256, 0, stream>>>(qkv, vT, attn_o);
    gemm_bt_kernel<false, true><<<dim3(1024/128, 8192/128), 256, 0, stream>>>(
        attn_o, wprojT, out, b_proj, Bdim*Nseq, Dmod, Dmod);
}